// Round 7
// baseline (200.233 us; speedup 1.0000x reference)
//
#include <hip/hip_runtime.h>

// z = segment_sum(x[col], row) @ W.T    (softmax over [E,1] axis=1 == 1)
// Pipeline: bucket build (counting sort by dest, 64 rows/bucket) +
// xb = bf16(x) streaming cast + per-bucket LDS row-sort + segmented bf16
// gather-sum (128B/edge) + fused @W.T epilogue per bucket (proven ~free in R5).

#define NBMAX 1600   // buckets = ceil(N/64); N=100000 -> 1563
#define BCAP  2048   // per-tile edge capacity (mean/bucket ~1024)

__global__ __launch_bounds__(1024) void k_ghist(const int* __restrict__ ei,
                                                int* __restrict__ gcnt,
                                                int E, int NB) {
    __shared__ int h[NBMAX];
    for (int i = threadIdx.x; i < NB; i += 1024) h[i] = 0;
    __syncthreads();
    long stride = (long)gridDim.x * 1024;
    for (long i = (long)blockIdx.x * 1024 + threadIdx.x; i < E; i += stride)
        atomicAdd(&h[ei[i] >> 6], 1);
    __syncthreads();
    for (int i = threadIdx.x; i < NB; i += 1024) {
        int v = h[i];
        if (v) atomicAdd(&gcnt[i], v);
    }
}

__global__ __launch_bounds__(1024) void k_gscan(const int* __restrict__ gcnt,
                                                int* __restrict__ boff,
                                                int* __restrict__ gcur,
                                                int NB, int E) {
    __shared__ int a[2048], b2[2048];
    int t = threadIdx.x;
    for (int i = t; i < 2048; i += 1024) a[i] = (i < NB) ? gcnt[i] : 0;
    __syncthreads();
    int* src = a; int* dst = b2;
    for (int s = 1; s < 2048; s <<= 1) {
        for (int i = t; i < 2048; i += 1024)
            dst[i] = src[i] + ((i >= s) ? src[i - s] : 0);
        __syncthreads();
        int* tmp = src; src = dst; dst = tmp;
    }
    for (int i = t; i < NB; i += 1024) {
        int excl = src[i] - gcnt[i];
        boff[i] = excl;
        gcur[i] = excl;
    }
    if (t == 0) boff[NB] = E;
}

__global__ __launch_bounds__(1024) void k_pairs(const int* __restrict__ ei,
                                                int* __restrict__ gcur,
                                                unsigned* __restrict__ pairs,
                                                int E, int NB) {
    __shared__ int hist[NBMAX];
    int t = threadIdx.x;
    long cb = (long)blockIdx.x * 8192;
    for (int i = t; i < NB; i += 1024) hist[i] = 0;
    int rows[8], cols[8];
    #pragma unroll
    for (int u = 0; u < 8; ++u) {
        long i = cb + (long)u * 1024 + t;
        rows[u] = (i < E) ? ei[i] : -1;
        cols[u] = (i < E) ? ei[(long)E + i] : 0;
    }
    __syncthreads();
    #pragma unroll
    for (int u = 0; u < 8; ++u)
        if (rows[u] >= 0) atomicAdd(&hist[rows[u] >> 6], 1);
    __syncthreads();
    for (int b = t; b < NB; b += 1024) {
        int c = hist[b];
        hist[b] = c ? atomicAdd(&gcur[b], c) : 0;
    }
    __syncthreads();
    #pragma unroll
    for (int u = 0; u < 8; ++u)
        if (rows[u] >= 0) {
            int p = atomicAdd(&hist[rows[u] >> 6], 1);
            pairs[p] = ((unsigned)(rows[u] & 63) << 26) | (unsigned)cols[u];
        }
}

__device__ __forceinline__ unsigned short f2bf(float f) {
    unsigned u = __float_as_uint(f);
    u = (u + 0x7fffu + ((u >> 16) & 1u)) >> 16;   // RNE
    return (unsigned short)u;
}

// Streaming cast: xb[i] = bf16(x[i]). 8 floats/thread, grid-stride.
__global__ __launch_bounds__(256) void k_cast(const float* __restrict__ x,
                                              unsigned short* __restrict__ xb,
                                              long n8) {
    long stride = (long)gridDim.x * 256;
    for (long i = (long)blockIdx.x * 256 + threadIdx.x; i < n8; i += stride) {
        const float4 a = *reinterpret_cast<const float4*>(x + i * 8);
        const float4 b = *reinterpret_cast<const float4*>(x + i * 8 + 4);
        uint4 o;
        o.x = (unsigned)f2bf(a.x) | ((unsigned)f2bf(a.y) << 16);
        o.y = (unsigned)f2bf(a.z) | ((unsigned)f2bf(a.w) << 16);
        o.z = (unsigned)f2bf(b.x) | ((unsigned)f2bf(b.y) << 16);
        o.w = (unsigned)f2bf(b.z) | ((unsigned)f2bf(b.w) << 16);
        *reinterpret_cast<uint4*>(xb + i * 8) = o;
    }
}

__device__ __forceinline__ float bf2f(unsigned short u) {
    return __uint_as_float(((unsigned)u) << 16);
}

__device__ __forceinline__ void seg_sum(const unsigned short* __restrict__ y,
                                        const int* scol, int rs, int re,
                                        int lane, float& acc) {
    int j = rs;
    for (; j + 8 <= re; j += 8) {        // 8 outstanding 128B row-loads
        int c0 = scol[j], c1 = scol[j+1], c2 = scol[j+2], c3 = scol[j+3];
        int c4 = scol[j+4], c5 = scol[j+5], c6 = scol[j+6], c7 = scol[j+7];
        float v0 = bf2f(y[(c0 << 6) + lane]);
        float v1 = bf2f(y[(c1 << 6) + lane]);
        float v2 = bf2f(y[(c2 << 6) + lane]);
        float v3 = bf2f(y[(c3 << 6) + lane]);
        float v4 = bf2f(y[(c4 << 6) + lane]);
        float v5 = bf2f(y[(c5 << 6) + lane]);
        float v6 = bf2f(y[(c6 << 6) + lane]);
        float v7 = bf2f(y[(c7 << 6) + lane]);
        acc += ((v0 + v1) + (v2 + v3)) + ((v4 + v5) + (v6 + v7));
    }
    for (; j + 4 <= re; j += 4) {
        int c0 = scol[j], c1 = scol[j+1], c2 = scol[j+2], c3 = scol[j+3];
        float v0 = bf2f(y[(c0 << 6) + lane]);
        float v1 = bf2f(y[(c1 << 6) + lane]);
        float v2 = bf2f(y[(c2 << 6) + lane]);
        float v3 = bf2f(y[(c3 << 6) + lane]);
        acc += (v0 + v1) + (v2 + v3);
    }
    for (; j < re; ++j) acc += bf2f(y[(scol[j] << 6) + lane]);
}

// Block (16 waves) per bucket; LDS counting-sort by row; wave wv owns rows
// 4wv..4wv+3; bf16 gather-sum in f32; fused @W.T epilogue + coalesced write.
__global__ __launch_bounds__(1024, 8) void k_bgather16f(
    const unsigned short* __restrict__ xb, const unsigned* __restrict__ pairs,
    const int* __restrict__ boff, const float* __restrict__ W,
    float* __restrict__ out, int N)
{
    __shared__ float w[64][65];       // 16.6KB; (65c+k)%32=(c+k)%32 -> 2-way only
    __shared__ float rowacc[64][64];  // 16KB
    __shared__ unsigned spv[BCAP];    // 8KB
    __shared__ int scol[BCAP];        // 8KB
    __shared__ int cnt[64];
    __shared__ int cs[65];
    int t = threadIdx.x, lane = t & 63, wv = t >> 6;   // 16 waves
    for (int i = t; i < 4096; i += 1024) w[i >> 6][i & 63] = W[i];
    int b = blockIdx.x;
    int s = boff[b], e = boff[b + 1];
    float acc0 = 0.f, acc1 = 0.f, acc2 = 0.f, acc3 = 0.f;

    for (int tile = s; tile < e; tile += BCAP) {
        int m = e - tile; if (m > BCAP) m = BCAP;
        if (t < 64) cnt[t] = 0;
        __syncthreads();
        for (int i = t; i < m; i += 1024) {
            unsigned pv = pairs[tile + i];
            spv[i] = pv;
            atomicAdd(&cnt[pv >> 26], 1);
        }
        __syncthreads();
        if (wv == 0) {                       // 64-wide exclusive scan, wave 0
            int c0 = cnt[lane];
            int v = c0;
            #pragma unroll
            for (int o = 1; o < 64; o <<= 1) {
                int u = __shfl_up(v, o, 64);
                if (lane >= o) v += u;
            }
            cs[lane + 1] = v;
            if (lane == 0) cs[0] = 0;
            cnt[lane] = v - c0;              // cursor = exclusive prefix
        }
        __syncthreads();
        for (int i = t; i < m; i += 1024) {
            unsigned pv = spv[i];
            int p = atomicAdd(&cnt[pv >> 26], 1);
            scol[p] = (int)(pv & 0x3FFFFFFu);
        }
        __syncthreads();

        int r4 = wv << 2;
        int b0 = cs[r4], b1 = cs[r4 + 1], b2 = cs[r4 + 2];
        int b3 = cs[r4 + 3], b4 = cs[r4 + 4];
        seg_sum(xb, scol, b0, b1, lane, acc0);
        seg_sum(xb, scol, b1, b2, lane, acc1);
        seg_sum(xb, scol, b2, b3, lane, acc2);
        seg_sum(xb, scol, b3, b4, lane, acc3);
        __syncthreads();                     // protect cnt/cs/spv/scol for next tile
    }

    rowacc[(wv << 2) + 0][lane] = acc0;
    rowacc[(wv << 2) + 1][lane] = acc1;
    rowacc[(wv << 2) + 2][lane] = acc2;
    rowacc[(wv << 2) + 3][lane] = acc3;
    __syncthreads();                         // also covers w-staging (empty buckets)
    int base = b << 6;
    int nr = N - base; if (nr > 64) nr = 64;
    for (int r = wv; r < nr; r += 16) {
        float z = 0.f;
        #pragma unroll
        for (int k = 0; k < 64; ++k)
            z += rowacc[r][k] * w[lane][k];  // rowacc[r][k] wave-uniform -> broadcast
        out[(long)(base + r) * 64 + lane] = z;
    }
}

// ---- tier-2 fallback: f32 gather with fused transform (R5 path) ----
__global__ __launch_bounds__(1024, 8) void k_bgather(
    const float* __restrict__ x, const unsigned* __restrict__ pairs,
    const int* __restrict__ boff, const float* __restrict__ W,
    float* __restrict__ out, int N)
{
    __shared__ float w[64][65];
    __shared__ float rowacc[64][64];
    __shared__ unsigned spv[BCAP];
    __shared__ int scol[BCAP];
    __shared__ int cnt[64];
    __shared__ int cs[65];
    int t = threadIdx.x, lane = t & 63, wv = t >> 6;
    for (int i = t; i < 4096; i += 1024) w[i >> 6][i & 63] = W[i];
    int b = blockIdx.x;
    int s = boff[b], e = boff[b + 1];
    float acc0 = 0.f, acc1 = 0.f, acc2 = 0.f, acc3 = 0.f;
    for (int tile = s; tile < e; tile += BCAP) {
        int m = e - tile; if (m > BCAP) m = BCAP;
        if (t < 64) cnt[t] = 0;
        __syncthreads();
        for (int i = t; i < m; i += 1024) {
            unsigned pv = pairs[tile + i];
            spv[i] = pv;
            atomicAdd(&cnt[pv >> 26], 1);
        }
        __syncthreads();
        if (wv == 0) {
            int c0 = cnt[lane];
            int v = c0;
            #pragma unroll
            for (int o = 1; o < 64; o <<= 1) {
                int u = __shfl_up(v, o, 64);
                if (lane >= o) v += u;
            }
            cs[lane + 1] = v;
            if (lane == 0) cs[0] = 0;
            cnt[lane] = v - c0;
        }
        __syncthreads();
        for (int i = t; i < m; i += 1024) {
            unsigned pv = spv[i];
            int p = atomicAdd(&cnt[pv >> 26], 1);
            scol[p] = (int)(pv & 0x3FFFFFFu);
        }
        __syncthreads();
        int r4 = wv << 2;
        int b0 = cs[r4], b1 = cs[r4 + 1], b2 = cs[r4 + 2];
        int b3 = cs[r4 + 3], b4 = cs[r4 + 4];
        int j = b0;
        for (; j < b1; ++j) acc0 += x[(long)scol[j] * 64 + lane];
        for (; j < b2; ++j) acc1 += x[(long)scol[j] * 64 + lane];
        for (; j < b3; ++j) acc2 += x[(long)scol[j] * 64 + lane];
        for (; j < b4; ++j) acc3 += x[(long)scol[j] * 64 + lane];
        __syncthreads();
    }
    rowacc[(wv << 2) + 0][lane] = acc0;
    rowacc[(wv << 2) + 1][lane] = acc1;
    rowacc[(wv << 2) + 2][lane] = acc2;
    rowacc[(wv << 2) + 3][lane] = acc3;
    __syncthreads();
    int base = b << 6;
    int nr = N - base; if (nr > 64) nr = 64;
    for (int r = wv; r < nr; r += 16) {
        float z = 0.f;
        #pragma unroll
        for (int k = 0; k < 64; ++k)
            z += rowacc[r][k] * w[lane][k];
        out[(long)(base + r) * 64 + lane] = z;
    }
}

// ---- tier-3 fallback (atomic scatter) ----
__global__ __launch_bounds__(256) void egat_scatter(const float* __restrict__ x,
                                                    const int* __restrict__ ei,
                                                    float* __restrict__ out, int E) {
    long tid = (long)blockIdx.x * blockDim.x + threadIdx.x;
    long e = tid >> 4;
    if (e >= E) return;
    int c4 = (int)(tid & 15) << 2;
    int row = ei[e];
    int col = ei[(long)E + e];
    const float4 v = *reinterpret_cast<const float4*>(x + (long)col * 64 + c4);
    float* o = out + (long)row * 64 + c4;
    atomicAdd(o + 0, v.x); atomicAdd(o + 1, v.y);
    atomicAdd(o + 2, v.z); atomicAdd(o + 3, v.w);
}

__global__ __launch_bounds__(256) void egat_transform(float* __restrict__ out,
                                                      const float* __restrict__ W, int N) {
    __shared__ float a[16][64];
    __shared__ float w[64][65];
    int t = threadIdx.x;
    for (int i = t; i < 64 * 64; i += 256) w[i >> 6][i & 63] = W[i];
    long r0 = (long)blockIdx.x * 16;
    int c = t & 63, rb = t >> 6;
    #pragma unroll
    for (int j = 0; j < 4; ++j) {
        long r = r0 + rb + 4 * j;
        if (r < N) a[rb + 4 * j][c] = out[r * 64 + c];
    }
    __syncthreads();
    float acc[4] = {0.f, 0.f, 0.f, 0.f};
    #pragma unroll
    for (int k = 0; k < 64; ++k) {
        float wk = w[c][k];
        #pragma unroll
        for (int j = 0; j < 4; ++j) acc[j] += a[rb + 4 * j][k] * wk;
    }
    #pragma unroll
    for (int j = 0; j < 4; ++j) {
        long r = r0 + rb + 4 * j;
        if (r < N) out[r * 64 + c] = acc[j];
    }
}

extern "C" void kernel_launch(void* const* d_in, const int* in_sizes, int n_in,
                              void* d_out, int out_size, void* d_ws, size_t ws_size,
                              hipStream_t stream)
{
    const float* x  = (const float*)d_in[0];
    const int*   ei = (const int*)d_in[1];
    const float* W  = (const float*)d_in[3];
    float* out = (float*)d_out;

    const int E  = in_sizes[1] / 2;
    const int N  = out_size / 64;
    const int NB = (N + 63) >> 6;

    // ws layout: gcnt[NB] | boff[NB+1] | gcur[NB] | pairs[E] | xb[N*64 bf16]
    size_t need_ints = ((size_t)NB * 3 + 1 + E) * sizeof(int);
    size_t need_bf16 = need_ints + (size_t)N * 64 * sizeof(unsigned short);
    if (NB <= NBMAX && ws_size >= need_bf16 && ((long)N * 64 % 8 == 0)) {
        int* gcnt = (int*)d_ws;
        int* boff = gcnt + NB;
        int* gcur = boff + (NB + 1);
        unsigned* pairs = (unsigned*)(gcur + NB);
        unsigned short* xb = (unsigned short*)(pairs + E);

        hipMemsetAsync(gcnt, 0, (size_t)NB * sizeof(int), stream);
        k_ghist<<<128, 1024, 0, stream>>>(ei, gcnt, E, NB);
        k_gscan<<<1, 1024, 0, stream>>>(gcnt, boff, gcur, NB, E);
        k_pairs<<<(E + 8191) / 8192, 1024, 0, stream>>>(ei, gcur, pairs, E, NB);
        long n8 = (long)N * 64 / 8;
        int cgrid = (int)((n8 + 255) / 256); if (cgrid > 2048) cgrid = 2048;
        k_cast<<<cgrid, 256, 0, stream>>>(x, xb, n8);
        k_bgather16f<<<NB, 1024, 0, stream>>>(xb, pairs, boff, W, out, N);
    } else if (NB <= NBMAX && ws_size >= need_ints) {
        int* gcnt = (int*)d_ws;
        int* boff = gcnt + NB;
        int* gcur = boff + (NB + 1);
        unsigned* pairs = (unsigned*)(gcur + NB);

        hipMemsetAsync(gcnt, 0, (size_t)NB * sizeof(int), stream);
        k_ghist<<<128, 1024, 0, stream>>>(ei, gcnt, E, NB);
        k_gscan<<<1, 1024, 0, stream>>>(gcnt, boff, gcur, NB, E);
        k_pairs<<<(E + 8191) / 8192, 1024, 0, stream>>>(ei, gcur, pairs, E, NB);
        k_bgather<<<NB, 1024, 0, stream>>>(x, pairs, boff, W, out, N);
    } else {
        hipMemsetAsync(out, 0, (size_t)N * 64 * sizeof(float), stream);
        long sthreads = (long)E * 16;
        egat_scatter<<<(int)((sthreads + 255) / 256), 256, 0, stream>>>(x, ei, out, E);
        egat_transform<<<(N + 15) / 16, 256, 0, stream>>>(out, W, N);
    }
}

// Round 8
// 122.823 us; speedup vs baseline: 1.6303x; 1.6303x over previous
//
#include <hip/hip_runtime.h>

// z = segment_sum(x[col], row) @ W.T    (softmax over [E,1] axis=1 == 1)
//   = segment_sum(y[col], row),  y = bf16(x @ W.T)   (linearity)
// build (counting sort by dest, 64 rows/bucket, ~30us) + y-transform
// (register-blocked VALU GEMM) + per-bucket sorted bf16 gather (~48us),
// gather writes out directly (NO in-gather epilogue: measured +110us in R4/5/7).

#define NBMAX 1600   // buckets = ceil(N/64); N=100000 -> 1563
#define BCAP  2048   // per-tile edge capacity (mean/bucket ~1024)

__global__ __launch_bounds__(1024) void k_ghist(const int* __restrict__ ei,
                                                int* __restrict__ gcnt,
                                                int E, int NB) {
    __shared__ int h[NBMAX];
    for (int i = threadIdx.x; i < NB; i += 1024) h[i] = 0;
    __syncthreads();
    long stride = (long)gridDim.x * 1024;
    for (long i = (long)blockIdx.x * 1024 + threadIdx.x; i < E; i += stride)
        atomicAdd(&h[ei[i] >> 6], 1);
    __syncthreads();
    for (int i = threadIdx.x; i < NB; i += 1024) {
        int v = h[i];
        if (v) atomicAdd(&gcnt[i], v);
    }
}

__global__ __launch_bounds__(1024) void k_gscan(const int* __restrict__ gcnt,
                                                int* __restrict__ boff,
                                                int* __restrict__ gcur,
                                                int NB, int E) {
    __shared__ int a[2048], b2[2048];
    int t = threadIdx.x;
    for (int i = t; i < 2048; i += 1024) a[i] = (i < NB) ? gcnt[i] : 0;
    __syncthreads();
    int* src = a; int* dst = b2;
    for (int s = 1; s < 2048; s <<= 1) {
        for (int i = t; i < 2048; i += 1024)
            dst[i] = src[i] + ((i >= s) ? src[i - s] : 0);
        __syncthreads();
        int* tmp = src; src = dst; dst = tmp;
    }
    for (int i = t; i < NB; i += 1024) {
        int excl = src[i] - gcnt[i];
        boff[i] = excl;
        gcur[i] = excl;
    }
    if (t == 0) boff[NB] = E;
}

__global__ __launch_bounds__(1024) void k_pairs(const int* __restrict__ ei,
                                                int* __restrict__ gcur,
                                                unsigned* __restrict__ pairs,
                                                int E, int NB) {
    __shared__ int hist[NBMAX];
    int t = threadIdx.x;
    long cb = (long)blockIdx.x * 8192;
    for (int i = t; i < NB; i += 1024) hist[i] = 0;
    int rows[8], cols[8];
    #pragma unroll
    for (int u = 0; u < 8; ++u) {
        long i = cb + (long)u * 1024 + t;
        rows[u] = (i < E) ? ei[i] : -1;
        cols[u] = (i < E) ? ei[(long)E + i] : 0;
    }
    __syncthreads();
    #pragma unroll
    for (int u = 0; u < 8; ++u)
        if (rows[u] >= 0) atomicAdd(&hist[rows[u] >> 6], 1);
    __syncthreads();
    for (int b = t; b < NB; b += 1024) {
        int c = hist[b];
        hist[b] = c ? atomicAdd(&gcur[b], c) : 0;
    }
    __syncthreads();
    #pragma unroll
    for (int u = 0; u < 8; ++u)
        if (rows[u] >= 0) {
            int p = atomicAdd(&hist[rows[u] >> 6], 1);
            pairs[p] = ((unsigned)(rows[u] & 63) << 26) | (unsigned)cols[u];
        }
}

__device__ __forceinline__ unsigned short f2bf(float f) {
    unsigned u = __float_as_uint(f);
    u = (u + 0x7fffu + ((u >> 16) & 1u)) >> 16;   // RNE
    return (unsigned short)u;
}
__device__ __forceinline__ float bf2f(unsigned short u) {
    return __uint_as_float(((unsigned)u) << 16);
}

// y = bf16(x @ W.T), 64 rows/block, 4x4 register tile per thread.
// Per k: 1 ds_read_b128 (wT) + 4 broadcast b32 (a) + 16 FMA.
__global__ __launch_bounds__(256) void k_ytrans2(const float* __restrict__ x,
                                                 const float* __restrict__ W,
                                                 unsigned short* __restrict__ y,
                                                 int N) {
    __shared__ float wT[64][68];   // wT[k][c]=W[c][k]; stride 68: b128-aligned reads
    __shared__ float a[64][65];    // stride 65: (r+k)%32 -> 4 distinct banks on reads
    int t = threadIdx.x;
    for (int i = t; i < 4096; i += 256) {
        int c = i >> 6, k = i & 63;
        wT[k][c] = W[i];                      // coalesced global read
    }
    long r0 = (long)blockIdx.x * 64;
    int nr = (int)(N - r0); if (nr > 64) nr = 64;
    for (int i = t; i < 1024; i += 256) {     // 1024 float4 = 64x64 tile
        int r = i >> 4, c4 = (i & 15) << 2;
        float4 v = (r < nr) ? *reinterpret_cast<const float4*>(x + (r0 + r) * 64 + c4)
                            : make_float4(0.f, 0.f, 0.f, 0.f);
        a[r][c4 + 0] = v.x; a[r][c4 + 1] = v.y;
        a[r][c4 + 2] = v.z; a[r][c4 + 3] = v.w;
    }
    __syncthreads();
    int tc = (t & 15) << 2;       // 4 consecutive cols
    int tr = t >> 4;              // rows tr + 16*j
    float acc[4][4] = {};
    #pragma unroll 8
    for (int k = 0; k < 64; ++k) {
        const float4 wv = *reinterpret_cast<const float4*>(&wT[k][tc]);
        float a0 = a[tr][k], a1 = a[tr + 16][k], a2 = a[tr + 32][k], a3 = a[tr + 48][k];
        acc[0][0] += a0 * wv.x; acc[0][1] += a0 * wv.y; acc[0][2] += a0 * wv.z; acc[0][3] += a0 * wv.w;
        acc[1][0] += a1 * wv.x; acc[1][1] += a1 * wv.y; acc[1][2] += a1 * wv.z; acc[1][3] += a1 * wv.w;
        acc[2][0] += a2 * wv.x; acc[2][1] += a2 * wv.y; acc[2][2] += a2 * wv.z; acc[2][3] += a2 * wv.w;
        acc[3][0] += a3 * wv.x; acc[3][1] += a3 * wv.y; acc[3][2] += a3 * wv.z; acc[3][3] += a3 * wv.w;
    }
    #pragma unroll
    for (int j = 0; j < 4; ++j) {
        long r = r0 + tr + 16 * j;
        if (r < N) {
            ushort4 o;
            o.x = f2bf(acc[j][0]); o.y = f2bf(acc[j][1]);
            o.z = f2bf(acc[j][2]); o.w = f2bf(acc[j][3]);
            *reinterpret_cast<ushort4*>(y + r * 64 + tc) = o;
        }
    }
}

__device__ __forceinline__ void seg_sum(const unsigned short* __restrict__ y,
                                        const int* scol, int rs, int re,
                                        int lane, float& acc) {
    int j = rs;
    for (; j + 8 <= re; j += 8) {        // 8 outstanding 128B row-loads
        int c0 = scol[j], c1 = scol[j+1], c2 = scol[j+2], c3 = scol[j+3];
        int c4 = scol[j+4], c5 = scol[j+5], c6 = scol[j+6], c7 = scol[j+7];
        float v0 = bf2f(y[(c0 << 6) + lane]);
        float v1 = bf2f(y[(c1 << 6) + lane]);
        float v2 = bf2f(y[(c2 << 6) + lane]);
        float v3 = bf2f(y[(c3 << 6) + lane]);
        float v4 = bf2f(y[(c4 << 6) + lane]);
        float v5 = bf2f(y[(c5 << 6) + lane]);
        float v6 = bf2f(y[(c6 << 6) + lane]);
        float v7 = bf2f(y[(c7 << 6) + lane]);
        acc += ((v0 + v1) + (v2 + v3)) + ((v4 + v5) + (v6 + v7));
    }
    for (; j + 4 <= re; j += 4) {
        int c0 = scol[j], c1 = scol[j+1], c2 = scol[j+2], c3 = scol[j+3];
        float v0 = bf2f(y[(c0 << 6) + lane]);
        float v1 = bf2f(y[(c1 << 6) + lane]);
        float v2 = bf2f(y[(c2 << 6) + lane]);
        float v3 = bf2f(y[(c3 << 6) + lane]);
        acc += (v0 + v1) + (v2 + v3);
    }
    for (; j < re; ++j) acc += bf2f(y[(scol[j] << 6) + lane]);
}

// Block (16 waves) per bucket; LDS counting-sort by row; wave wv owns rows
// 4wv..4wv+3; bf16 gather-sum in f32; DIRECT out write (no epilogue).
__global__ __launch_bounds__(1024, 8) void k_bgather16(
    const unsigned short* __restrict__ y, const unsigned* __restrict__ pairs,
    const int* __restrict__ boff, float* __restrict__ out, int N)
{
    __shared__ unsigned spv[BCAP];    // 8KB
    __shared__ int scol[BCAP];        // 8KB
    __shared__ int cnt[64];
    __shared__ int cs[65];
    int t = threadIdx.x, lane = t & 63, wv = t >> 6;   // 16 waves
    int b = blockIdx.x;
    int s = boff[b], e = boff[b + 1];
    float acc0 = 0.f, acc1 = 0.f, acc2 = 0.f, acc3 = 0.f;

    for (int tile = s; tile < e; tile += BCAP) {
        int m = e - tile; if (m > BCAP) m = BCAP;
        if (t < 64) cnt[t] = 0;
        __syncthreads();
        for (int i = t; i < m; i += 1024) {
            unsigned pv = pairs[tile + i];
            spv[i] = pv;
            atomicAdd(&cnt[pv >> 26], 1);
        }
        __syncthreads();
        if (wv == 0) {                       // 64-wide exclusive scan, wave 0
            int c0 = cnt[lane];
            int v = c0;
            #pragma unroll
            for (int o = 1; o < 64; o <<= 1) {
                int u = __shfl_up(v, o, 64);
                if (lane >= o) v += u;
            }
            cs[lane + 1] = v;
            if (lane == 0) cs[0] = 0;
            cnt[lane] = v - c0;              // cursor = exclusive prefix
        }
        __syncthreads();
        for (int i = t; i < m; i += 1024) {
            unsigned pv = spv[i];
            int p = atomicAdd(&cnt[pv >> 26], 1);
            scol[p] = (int)(pv & 0x3FFFFFFu);
        }
        __syncthreads();

        int r4 = wv << 2;
        int b0 = cs[r4], b1 = cs[r4 + 1], b2 = cs[r4 + 2];
        int b3 = cs[r4 + 3], b4 = cs[r4 + 4];
        seg_sum(y, scol, b0, b1, lane, acc0);
        seg_sum(y, scol, b1, b2, lane, acc1);
        seg_sum(y, scol, b2, b3, lane, acc2);
        seg_sum(y, scol, b3, b4, lane, acc3);
        __syncthreads();                     // protect cnt/cs/spv/scol for next tile
    }

    int base = (b << 6) + (wv << 2);
    if (base + 0 < N) out[(long)(base + 0) * 64 + lane] = acc0;
    if (base + 1 < N) out[(long)(base + 1) * 64 + lane] = acc1;
    if (base + 2 < N) out[(long)(base + 2) * 64 + lane] = acc2;
    if (base + 3 < N) out[(long)(base + 3) * 64 + lane] = acc3;
}

// ---- tier-2 fallback: f32 gather with fused transform ----
__global__ __launch_bounds__(1024, 8) void k_bgather(
    const float* __restrict__ x, const unsigned* __restrict__ pairs,
    const int* __restrict__ boff, const float* __restrict__ W,
    float* __restrict__ out, int N)
{
    __shared__ float w[64][65];
    __shared__ float rowacc[64][64];
    __shared__ unsigned spv[BCAP];
    __shared__ int scol[BCAP];
    __shared__ int cnt[64];
    __shared__ int cs[65];
    int t = threadIdx.x, lane = t & 63, wv = t >> 6;
    for (int i = t; i < 4096; i += 1024) w[i >> 6][i & 63] = W[i];
    int b = blockIdx.x;
    int s = boff[b], e = boff[b + 1];
    float acc0 = 0.f, acc1 = 0.f, acc2 = 0.f, acc3 = 0.f;
    for (int tile = s; tile < e; tile += BCAP) {
        int m = e - tile; if (m > BCAP) m = BCAP;
        if (t < 64) cnt[t] = 0;
        __syncthreads();
        for (int i = t; i < m; i += 1024) {
            unsigned pv = pairs[tile + i];
            spv[i] = pv;
            atomicAdd(&cnt[pv >> 26], 1);
        }
        __syncthreads();
        if (wv == 0) {
            int c0 = cnt[lane];
            int v = c0;
            #pragma unroll
            for (int o = 1; o < 64; o <<= 1) {
                int u = __shfl_up(v, o, 64);
                if (lane >= o) v += u;
            }
            cs[lane + 1] = v;
            if (lane == 0) cs[0] = 0;
            cnt[lane] = v - c0;
        }
        __syncthreads();
        for (int i = t; i < m; i += 1024) {
            unsigned pv = spv[i];
            int p = atomicAdd(&cnt[pv >> 26], 1);
            scol[p] = (int)(pv & 0x3FFFFFFu);
        }
        __syncthreads();
        int r4 = wv << 2;
        int b0 = cs[r4], b1 = cs[r4 + 1], b2 = cs[r4 + 2];
        int b3 = cs[r4 + 3], b4 = cs[r4 + 4];
        int j = b0;
        for (; j < b1; ++j) acc0 += x[(long)scol[j] * 64 + lane];
        for (; j < b2; ++j) acc1 += x[(long)scol[j] * 64 + lane];
        for (; j < b3; ++j) acc2 += x[(long)scol[j] * 64 + lane];
        for (; j < b4; ++j) acc3 += x[(long)scol[j] * 64 + lane];
        __syncthreads();
    }
    rowacc[(wv << 2) + 0][lane] = acc0;
    rowacc[(wv << 2) + 1][lane] = acc1;
    rowacc[(wv << 2) + 2][lane] = acc2;
    rowacc[(wv << 2) + 3][lane] = acc3;
    __syncthreads();
    int base = b << 6;
    int nr = N - base; if (nr > 64) nr = 64;
    for (int r = wv; r < nr; r += 16) {
        float z = 0.f;
        #pragma unroll
        for (int k = 0; k < 64; ++k)
            z += rowacc[r][k] * w[lane][k];
        out[(long)(base + r) * 64 + lane] = z;
    }
}

// ---- tier-3 fallback (atomic scatter) ----
__global__ __launch_bounds__(256) void egat_scatter(const float* __restrict__ x,
                                                    const int* __restrict__ ei,
                                                    float* __restrict__ out, int E) {
    long tid = (long)blockIdx.x * blockDim.x + threadIdx.x;
    long e = tid >> 4;
    if (e >= E) return;
    int c4 = (int)(tid & 15) << 2;
    int row = ei[e];
    int col = ei[(long)E + e];
    const float4 v = *reinterpret_cast<const float4*>(x + (long)col * 64 + c4);
    float* o = out + (long)row * 64 + c4;
    atomicAdd(o + 0, v.x); atomicAdd(o + 1, v.y);
    atomicAdd(o + 2, v.z); atomicAdd(o + 3, v.w);
}

__global__ __launch_bounds__(256) void egat_transform(float* __restrict__ out,
                                                      const float* __restrict__ W, int N) {
    __shared__ float a[16][64];
    __shared__ float w[64][65];
    int t = threadIdx.x;
    for (int i = t; i < 64 * 64; i += 256) w[i >> 6][i & 63] = W[i];
    long r0 = (long)blockIdx.x * 16;
    int c = t & 63, rb = t >> 6;
    #pragma unroll
    for (int j = 0; j < 4; ++j) {
        long r = r0 + rb + 4 * j;
        if (r < N) a[rb + 4 * j][c] = out[r * 64 + c];
    }
    __syncthreads();
    float acc[4] = {0.f, 0.f, 0.f, 0.f};
    #pragma unroll
    for (int k = 0; k < 64; ++k) {
        float wk = w[c][k];
        #pragma unroll
        for (int j = 0; j < 4; ++j) acc[j] += a[rb + 4 * j][k] * wk;
    }
    #pragma unroll
    for (int j = 0; j < 4; ++j) {
        long r = r0 + rb + 4 * j;
        if (r < N) out[r * 64 + c] = acc[j];
    }
}

extern "C" void kernel_launch(void* const* d_in, const int* in_sizes, int n_in,
                              void* d_out, int out_size, void* d_ws, size_t ws_size,
                              hipStream_t stream)
{
    const float* x  = (const float*)d_in[0];
    const int*   ei = (const int*)d_in[1];
    const float* W  = (const float*)d_in[3];
    float* out = (float*)d_out;

    const int E  = in_sizes[1] / 2;
    const int N  = out_size / 64;
    const int NB = (N + 63) >> 6;

    // ws layout: gcnt[NB] | boff[NB+1] | gcur[NB] | pairs[E] | y[N*64 bf16]
    size_t need_ints = ((size_t)NB * 3 + 1 + E) * sizeof(int);
    size_t need_bf16 = need_ints + (size_t)N * 64 * sizeof(unsigned short);
    if (NB <= NBMAX && ws_size >= need_bf16) {
        int* gcnt = (int*)d_ws;
        int* boff = gcnt + NB;
        int* gcur = boff + (NB + 1);
        unsigned* pairs = (unsigned*)(gcur + NB);
        unsigned short* y = (unsigned short*)(pairs + E);

        hipMemsetAsync(gcnt, 0, (size_t)NB * sizeof(int), stream);
        k_ghist<<<128, 1024, 0, stream>>>(ei, gcnt, E, NB);
        k_gscan<<<1, 1024, 0, stream>>>(gcnt, boff, gcur, NB, E);
        k_pairs<<<(E + 8191) / 8192, 1024, 0, stream>>>(ei, gcur, pairs, E, NB);
        k_ytrans2<<<(N + 63) / 64, 256, 0, stream>>>(x, W, y, N);
        k_bgather16<<<NB, 1024, 0, stream>>>(y, pairs, boff, out, N);
    } else if (NB <= NBMAX && ws_size >= need_ints) {
        int* gcnt = (int*)d_ws;
        int* boff = gcnt + NB;
        int* gcur = boff + (NB + 1);
        unsigned* pairs = (unsigned*)(gcur + NB);

        hipMemsetAsync(gcnt, 0, (size_t)NB * sizeof(int), stream);
        k_ghist<<<128, 1024, 0, stream>>>(ei, gcnt, E, NB);
        k_gscan<<<1, 1024, 0, stream>>>(gcnt, boff, gcur, NB, E);
        k_pairs<<<(E + 8191) / 8192, 1024, 0, stream>>>(ei, gcur, pairs, E, NB);
        k_bgather<<<NB, 1024, 0, stream>>>(x, pairs, boff, W, out, N);
    } else {
        hipMemsetAsync(out, 0, (size_t)N * 64 * sizeof(float), stream);
        long sthreads = (long)E * 16;
        egat_scatter<<<(int)((sthreads + 255) / 256), 256, 0, stream>>>(x, ei, out, E);
        egat_transform<<<(N + 15) / 16, 256, 0, stream>>>(out, W, N);
    }
}

// Round 9
// 112.350 us; speedup vs baseline: 1.7822x; 1.0932x over previous
//
#include <hip/hip_runtime.h>

// z = segment_sum(x[col], row) @ W.T  =  segment_sum(y[col], row), y = bf16(x@W.T)
// 3 dispatches:
//  1) k_ghist2 : 64-block LDS hist -> per-block partial counts (aliased into pairs[]),
//                block0 zeroes the release flag. No global atomics, no memset.
//  2) k_mega   : blk0 = sum partials + scan -> boff/gcur -> flag=1
//                blk 1..PB = pairs counting-sort chunks (spin on flag after local hist)
//                blk PB+1.. = ytrans (y = bf16(x@W.T)), independent, overlaps.
//  3) k_bgather16 : per-bucket LDS row-sort + dual-row 16-deep bf16 gather, direct out.

#define NBMAX 1600   // buckets = ceil(N/64)
#define BCAP  2048
#define GB    64     // ghist blocks

__global__ __launch_bounds__(1024) void k_ghist2(const int* __restrict__ ei,
                                                 int* __restrict__ part,
                                                 int* __restrict__ flag,
                                                 int E, int NB) {
    __shared__ int h[NBMAX];
    int t = threadIdx.x, blk = blockIdx.x;
    for (int i = t; i < NB; i += 1024) h[i] = 0;
    __syncthreads();
    long stride = (long)GB * 1024;
    for (long i = (long)blk * 1024 + t; i < E; i += stride)
        atomicAdd(&h[ei[i] >> 6], 1);
    __syncthreads();
    for (int i = t; i < NB; i += 1024) part[blk * NB + i] = h[i];
    if (blk == 0 && t == 0) flag[0] = 0;
}

// smem reused by role: scan needs 16KB, pairs 6.4KB, ytrans 34KB.
__global__ __launch_bounds__(1024) void k_mega(
    const int* __restrict__ ei, const float* __restrict__ x,
    const float* __restrict__ W, int* __restrict__ flag,
    int* __restrict__ boff, int* __restrict__ gcur,
    int* __restrict__ pairs /* partials alias the head */,
    unsigned short* __restrict__ y, int E, int N, int NB, int PB)
{
    __shared__ float smem[64 * 68 + 64 * 65];   // 34KB
    int t = threadIdx.x;
    int bid = blockIdx.x;

    if (bid == 0) {
        // ---- sum partials + exclusive scan ----
        int* a  = (int*)smem;
        int* b2 = a + 2048;
        for (int i = t; i < 2048; i += 1024) {
            int s = 0;
            if (i < NB)
                for (int blk = 0; blk < GB; ++blk) s += pairs[blk * NB + i];
            a[i] = s;
        }
        __syncthreads();
        int* src = a; int* dst = b2;
        for (int s = 1; s < 2048; s <<= 1) {
            for (int i = t; i < 2048; i += 1024)
                dst[i] = src[i] + ((i >= s) ? src[i - s] : 0);
            __syncthreads();
            int* tmp = src; src = dst; dst = tmp;
        }
        // recompute cnt to get exclusive prefix (src holds inclusive)
        for (int i = t; i < NB; i += 1024) {
            int incl = src[i];
            int cnt  = incl - ((i > 0) ? src[i - 1] : 0);
            boff[i] = incl - cnt;
            gcur[i] = incl - cnt;
        }
        if (t == 0) boff[NB] = E;
        __threadfence();
        __syncthreads();
        if (t == 0) atomicExch(flag, 1);     // release
    } else if (bid <= PB) {
        // ---- pairs chunk (bid-1) ----
        int* hist = (int*)smem;
        long cb = (long)(bid - 1) * 8192;
        for (int i = t; i < NB; i += 1024) hist[i] = 0;
        int rows[8], cols[8];
        #pragma unroll
        for (int u = 0; u < 8; ++u) {
            long i = cb + (long)u * 1024 + t;
            rows[u] = (i < E) ? ei[i] : -1;
            cols[u] = (i < E) ? ei[(long)E + i] : 0;
        }
        __syncthreads();
        #pragma unroll
        for (int u = 0; u < 8; ++u)
            if (rows[u] >= 0) atomicAdd(&hist[rows[u] >> 6], 1);
        // spin until scan published gcur (overlaps with ytrans blocks)
        if (t == 0) while (atomicAdd(flag, 0) == 0) __builtin_amdgcn_s_sleep(8);
        __syncthreads();
        for (int b = t; b < NB; b += 1024) {
            int c = hist[b];
            hist[b] = c ? atomicAdd(&gcur[b], c) : 0;
        }
        __syncthreads();
        #pragma unroll
        for (int u = 0; u < 8; ++u)
            if (rows[u] >= 0) {
                int p = atomicAdd(&hist[rows[u] >> 6], 1);
                pairs[p] = (int)(((unsigned)(rows[u] & 63) << 26) | (unsigned)cols[u]);
            }
    } else {
        // ---- ytrans block: 64 rows, 1024 threads, 1x4 tile/thread ----
        float (*wT)[68] = (float(*)[68])smem;            // wT[k][c] = W[c][k]
        float (*a)[65]  = (float(*)[65])(smem + 64 * 68);
        for (int i = t; i < 4096; i += 1024) {
            int c = i >> 6, k = i & 63;
            wT[k][c] = W[i];
        }
        long r0 = (long)(bid - 1 - PB) * 64;
        int nr = (int)(N - r0); if (nr > 64) nr = 64;
        {
            int r = t >> 4, c4 = (t & 15) << 2;
            float4 v = (r < nr) ? *reinterpret_cast<const float4*>(x + (r0 + r) * 64 + c4)
                                : make_float4(0.f, 0.f, 0.f, 0.f);
            a[r][c4 + 0] = v.x; a[r][c4 + 1] = v.y;
            a[r][c4 + 2] = v.z; a[r][c4 + 3] = v.w;
        }
        __syncthreads();
        int tc = (t & 15) << 2;
        int tr = t >> 4;                                  // 0..63
        float acc0 = 0.f, acc1 = 0.f, acc2 = 0.f, acc3 = 0.f;
        #pragma unroll 8
        for (int k = 0; k < 64; ++k) {
            const float4 wv = *reinterpret_cast<const float4*>(&wT[k][tc]);
            float av = a[tr][k];
            acc0 += av * wv.x; acc1 += av * wv.y;
            acc2 += av * wv.z; acc3 += av * wv.w;
        }
        long r = r0 + tr;
        if (r < N) {
            ushort4 o;
            unsigned u0 = __float_as_uint(acc0); u0 = (u0 + 0x7fffu + ((u0 >> 16) & 1u)) >> 16;
            unsigned u1 = __float_as_uint(acc1); u1 = (u1 + 0x7fffu + ((u1 >> 16) & 1u)) >> 16;
            unsigned u2 = __float_as_uint(acc2); u2 = (u2 + 0x7fffu + ((u2 >> 16) & 1u)) >> 16;
            unsigned u3 = __float_as_uint(acc3); u3 = (u3 + 0x7fffu + ((u3 >> 16) & 1u)) >> 16;
            o.x = (unsigned short)u0; o.y = (unsigned short)u1;
            o.z = (unsigned short)u2; o.w = (unsigned short)u3;
            *reinterpret_cast<ushort4*>(y + r * 64 + tc) = o;
        }
    }
}

__device__ __forceinline__ float bf2f(unsigned short u) {
    return __uint_as_float(((unsigned)u) << 16);
}

__device__ __forceinline__ void seg_tail(const unsigned short* __restrict__ y,
                                         const int* scol, int& j, int re,
                                         int lane, float& acc) {
    for (; j + 4 <= re; j += 4) {
        int c0 = scol[j], c1 = scol[j+1], c2 = scol[j+2], c3 = scol[j+3];
        float v0 = bf2f(y[(c0 << 6) + lane]);
        float v1 = bf2f(y[(c1 << 6) + lane]);
        float v2 = bf2f(y[(c2 << 6) + lane]);
        float v3 = bf2f(y[(c3 << 6) + lane]);
        acc += (v0 + v1) + (v2 + v3);
    }
    for (; j < re; ++j) acc += bf2f(y[(scol[j] << 6) + lane]);
}

__device__ __forceinline__ void seg_sum8(const unsigned short* __restrict__ y,
                                         const int* scol, int& j, int re,
                                         int lane, float& acc) {
    for (; j + 8 <= re; j += 8) {
        int c0 = scol[j], c1 = scol[j+1], c2 = scol[j+2], c3 = scol[j+3];
        int c4 = scol[j+4], c5 = scol[j+5], c6 = scol[j+6], c7 = scol[j+7];
        float v0 = bf2f(y[(c0 << 6) + lane]);
        float v1 = bf2f(y[(c1 << 6) + lane]);
        float v2 = bf2f(y[(c2 << 6) + lane]);
        float v3 = bf2f(y[(c3 << 6) + lane]);
        float v4 = bf2f(y[(c4 << 6) + lane]);
        float v5 = bf2f(y[(c5 << 6) + lane]);
        float v6 = bf2f(y[(c6 << 6) + lane]);
        float v7 = bf2f(y[(c7 << 6) + lane]);
        acc += ((v0 + v1) + (v2 + v3)) + ((v4 + v5) + (v6 + v7));
    }
}

// Dual-row: 16 outstanding 128B loads while both segments have >=8 left.
__device__ __forceinline__ void seg_sum2(const unsigned short* __restrict__ y,
                                         const int* scol, int j0, int e0,
                                         int j1, int e1, int lane,
                                         float& acc0, float& acc1) {
    while (j0 + 8 <= e0 && j1 + 8 <= e1) {
        int a0 = scol[j0], a1 = scol[j0+1], a2 = scol[j0+2], a3 = scol[j0+3];
        int a4 = scol[j0+4], a5 = scol[j0+5], a6 = scol[j0+6], a7 = scol[j0+7];
        int b0 = scol[j1], b1 = scol[j1+1], b2 = scol[j1+2], b3 = scol[j1+3];
        int b4 = scol[j1+4], b5 = scol[j1+5], b6 = scol[j1+6], b7 = scol[j1+7];
        float x0 = bf2f(y[(a0 << 6) + lane]), x1 = bf2f(y[(a1 << 6) + lane]);
        float x2 = bf2f(y[(a2 << 6) + lane]), x3 = bf2f(y[(a3 << 6) + lane]);
        float x4 = bf2f(y[(a4 << 6) + lane]), x5 = bf2f(y[(a5 << 6) + lane]);
        float x6 = bf2f(y[(a6 << 6) + lane]), x7 = bf2f(y[(a7 << 6) + lane]);
        float w0 = bf2f(y[(b0 << 6) + lane]), w1 = bf2f(y[(b1 << 6) + lane]);
        float w2 = bf2f(y[(b2 << 6) + lane]), w3 = bf2f(y[(b3 << 6) + lane]);
        float w4 = bf2f(y[(b4 << 6) + lane]), w5 = bf2f(y[(b5 << 6) + lane]);
        float w6 = bf2f(y[(b6 << 6) + lane]), w7 = bf2f(y[(b7 << 6) + lane]);
        acc0 += ((x0 + x1) + (x2 + x3)) + ((x4 + x5) + (x6 + x7));
        acc1 += ((w0 + w1) + (w2 + w3)) + ((w4 + w5) + (w6 + w7));
        j0 += 8; j1 += 8;
    }
    seg_sum8(y, scol, j0, e0, lane, acc0);
    seg_tail(y, scol, j0, e0, lane, acc0);
    seg_sum8(y, scol, j1, e1, lane, acc1);
    seg_tail(y, scol, j1, e1, lane, acc1);
}

__global__ __launch_bounds__(1024, 8) void k_bgather16(
    const unsigned short* __restrict__ y, const unsigned* __restrict__ pairs,
    const int* __restrict__ boff, float* __restrict__ out, int N)
{
    __shared__ unsigned spv[BCAP];
    __shared__ int scol[BCAP];
    __shared__ int cnt[64];
    __shared__ int cs[65];
    int t = threadIdx.x, lane = t & 63, wv = t >> 6;   // 16 waves
    int b = blockIdx.x;
    int s = boff[b], e = boff[b + 1];
    float acc0 = 0.f, acc1 = 0.f, acc2 = 0.f, acc3 = 0.f;

    for (int tile = s; tile < e; tile += BCAP) {
        int m = e - tile; if (m > BCAP) m = BCAP;
        if (t < 64) cnt[t] = 0;
        __syncthreads();
        for (int i = t; i < m; i += 1024) {
            unsigned pv = pairs[tile + i];
            spv[i] = pv;
            atomicAdd(&cnt[pv >> 26], 1);
        }
        __syncthreads();
        if (wv == 0) {
            int c0 = cnt[lane];
            int v = c0;
            #pragma unroll
            for (int o = 1; o < 64; o <<= 1) {
                int u = __shfl_up(v, o, 64);
                if (lane >= o) v += u;
            }
            cs[lane + 1] = v;
            if (lane == 0) cs[0] = 0;
            cnt[lane] = v - c0;
        }
        __syncthreads();
        for (int i = t; i < m; i += 1024) {
            unsigned pv = spv[i];
            int p = atomicAdd(&cnt[pv >> 26], 1);
            scol[p] = (int)(pv & 0x3FFFFFFu);
        }
        __syncthreads();

        int r4 = wv << 2;
        int b0 = cs[r4], b1 = cs[r4 + 1], b2 = cs[r4 + 2];
        int b3 = cs[r4 + 3], b4 = cs[r4 + 4];
        seg_sum2(y, scol, b0, b1, b1, b2, lane, acc0, acc1);
        seg_sum2(y, scol, b2, b3, b3, b4, lane, acc2, acc3);
        __syncthreads();
    }

    int base = (b << 6) + (wv << 2);
    if (base + 0 < N) out[(long)(base + 0) * 64 + lane] = acc0;
    if (base + 1 < N) out[(long)(base + 1) * 64 + lane] = acc1;
    if (base + 2 < N) out[(long)(base + 2) * 64 + lane] = acc2;
    if (base + 3 < N) out[(long)(base + 3) * 64 + lane] = acc3;
}

// ================= tier-2: R8 proven 5-dispatch path =================
__global__ __launch_bounds__(1024) void k_ghist(const int* __restrict__ ei,
                                                int* __restrict__ gcnt, int E, int NB) {
    __shared__ int h[NBMAX];
    for (int i = threadIdx.x; i < NB; i += 1024) h[i] = 0;
    __syncthreads();
    long stride = (long)gridDim.x * 1024;
    for (long i = (long)blockIdx.x * 1024 + threadIdx.x; i < E; i += stride)
        atomicAdd(&h[ei[i] >> 6], 1);
    __syncthreads();
    for (int i = threadIdx.x; i < NB; i += 1024) {
        int v = h[i];
        if (v) atomicAdd(&gcnt[i], v);
    }
}

__global__ __launch_bounds__(1024) void k_gscan(const int* __restrict__ gcnt,
                                                int* __restrict__ boff,
                                                int* __restrict__ gcur, int NB, int E) {
    __shared__ int a[2048], b2[2048];
    int t = threadIdx.x;
    for (int i = t; i < 2048; i += 1024) a[i] = (i < NB) ? gcnt[i] : 0;
    __syncthreads();
    int* src = a; int* dst = b2;
    for (int s = 1; s < 2048; s <<= 1) {
        for (int i = t; i < 2048; i += 1024)
            dst[i] = src[i] + ((i >= s) ? src[i - s] : 0);
        __syncthreads();
        int* tmp = src; src = dst; dst = tmp;
    }
    for (int i = t; i < NB; i += 1024) {
        int excl = src[i] - gcnt[i];
        boff[i] = excl;
        gcur[i] = excl;
    }
    if (t == 0) boff[NB] = E;
}

__global__ __launch_bounds__(1024) void k_pairs(const int* __restrict__ ei,
                                                int* __restrict__ gcur,
                                                unsigned* __restrict__ pairs, int E, int NB) {
    __shared__ int hist[NBMAX];
    int t = threadIdx.x;
    long cb = (long)blockIdx.x * 8192;
    for (int i = t; i < NB; i += 1024) hist[i] = 0;
    int rows[8], cols[8];
    #pragma unroll
    for (int u = 0; u < 8; ++u) {
        long i = cb + (long)u * 1024 + t;
        rows[u] = (i < E) ? ei[i] : -1;
        cols[u] = (i < E) ? ei[(long)E + i] : 0;
    }
    __syncthreads();
    #pragma unroll
    for (int u = 0; u < 8; ++u)
        if (rows[u] >= 0) atomicAdd(&hist[rows[u] >> 6], 1);
    __syncthreads();
    for (int b = t; b < NB; b += 1024) {
        int c = hist[b];
        hist[b] = c ? atomicAdd(&gcur[b], c) : 0;
    }
    __syncthreads();
    #pragma unroll
    for (int u = 0; u < 8; ++u)
        if (rows[u] >= 0) {
            int p = atomicAdd(&hist[rows[u] >> 6], 1);
            pairs[p] = ((unsigned)(rows[u] & 63) << 26) | (unsigned)cols[u];
        }
}

__device__ __forceinline__ unsigned short f2bf(float f) {
    unsigned u = __float_as_uint(f);
    u = (u + 0x7fffu + ((u >> 16) & 1u)) >> 16;
    return (unsigned short)u;
}

__global__ __launch_bounds__(256) void k_ytrans2(const float* __restrict__ x,
                                                 const float* __restrict__ W,
                                                 unsigned short* __restrict__ y, int N) {
    __shared__ float wT[64][68];
    __shared__ float a[64][65];
    int t = threadIdx.x;
    for (int i = t; i < 4096; i += 256) {
        int c = i >> 6, k = i & 63;
        wT[k][c] = W[i];
    }
    long r0 = (long)blockIdx.x * 64;
    int nr = (int)(N - r0); if (nr > 64) nr = 64;
    for (int i = t; i < 1024; i += 256) {
        int r = i >> 4, c4 = (i & 15) << 2;
        float4 v = (r < nr) ? *reinterpret_cast<const float4*>(x + (r0 + r) * 64 + c4)
                            : make_float4(0.f, 0.f, 0.f, 0.f);
        a[r][c4 + 0] = v.x; a[r][c4 + 1] = v.y;
        a[r][c4 + 2] = v.z; a[r][c4 + 3] = v.w;
    }
    __syncthreads();
    int tc = (t & 15) << 2;
    int tr = t >> 4;
    float acc[4][4] = {};
    #pragma unroll 8
    for (int k = 0; k < 64; ++k) {
        const float4 wv = *reinterpret_cast<const float4*>(&wT[k][tc]);
        float a0 = a[tr][k], a1 = a[tr + 16][k], a2 = a[tr + 32][k], a3 = a[tr + 48][k];
        acc[0][0] += a0 * wv.x; acc[0][1] += a0 * wv.y; acc[0][2] += a0 * wv.z; acc[0][3] += a0 * wv.w;
        acc[1][0] += a1 * wv.x; acc[1][1] += a1 * wv.y; acc[1][2] += a1 * wv.z; acc[1][3] += a1 * wv.w;
        acc[2][0] += a2 * wv.x; acc[2][1] += a2 * wv.y; acc[2][2] += a2 * wv.z; acc[2][3] += a2 * wv.w;
        acc[3][0] += a3 * wv.x; acc[3][1] += a3 * wv.y; acc[3][2] += a3 * wv.z; acc[3][3] += a3 * wv.w;
    }
    #pragma unroll
    for (int j = 0; j < 4; ++j) {
        long r = r0 + tr + 16 * j;
        if (r < N) {
            ushort4 o;
            o.x = f2bf(acc[j][0]); o.y = f2bf(acc[j][1]);
            o.z = f2bf(acc[j][2]); o.w = f2bf(acc[j][3]);
            *reinterpret_cast<ushort4*>(y + r * 64 + tc) = o;
        }
    }
}

// ---- tier-3 fallback (atomic scatter) ----
__global__ __launch_bounds__(256) void egat_scatter(const float* __restrict__ x,
                                                    const int* __restrict__ ei,
                                                    float* __restrict__ out, int E) {
    long tid = (long)blockIdx.x * blockDim.x + threadIdx.x;
    long e = tid >> 4;
    if (e >= E) return;
    int c4 = (int)(tid & 15) << 2;
    int row = ei[e];
    int col = ei[(long)E + e];
    const float4 v = *reinterpret_cast<const float4*>(x + (long)col * 64 + c4);
    float* o = out + (long)row * 64 + c4;
    atomicAdd(o + 0, v.x); atomicAdd(o + 1, v.y);
    atomicAdd(o + 2, v.z); atomicAdd(o + 3, v.w);
}

__global__ __launch_bounds__(256) void egat_transform(float* __restrict__ out,
                                                      const float* __restrict__ W, int N) {
    __shared__ float a[16][64];
    __shared__ float w[64][65];
    int t = threadIdx.x;
    for (int i = t; i < 64 * 64; i += 256) w[i >> 6][i & 63] = W[i];
    long r0 = (long)blockIdx.x * 16;
    int c = t & 63, rb = t >> 6;
    #pragma unroll
    for (int j = 0; j < 4; ++j) {
        long r = r0 + rb + 4 * j;
        if (r < N) a[rb + 4 * j][c] = out[r * 64 + c];
    }
    __syncthreads();
    float acc[4] = {0.f, 0.f, 0.f, 0.f};
    #pragma unroll
    for (int k = 0; k < 64; ++k) {
        float wk = w[c][k];
        #pragma unroll
        for (int j = 0; j < 4; ++j) acc[j] += a[rb + 4 * j][k] * wk;
    }
    #pragma unroll
    for (int j = 0; j < 4; ++j) {
        long r = r0 + rb + 4 * j;
        if (r < N) out[r * 64 + c] = acc[j];
    }
}

extern "C" void kernel_launch(void* const* d_in, const int* in_sizes, int n_in,
                              void* d_out, int out_size, void* d_ws, size_t ws_size,
                              hipStream_t stream)
{
    const float* x  = (const float*)d_in[0];
    const int*   ei = (const int*)d_in[1];
    const float* W  = (const float*)d_in[3];
    float* out = (float*)d_out;

    const int E  = in_sizes[1] / 2;
    const int N  = out_size / 64;
    const int NB = (N + 63) >> 6;
    const int PB = (E + 8191) / 8192;
    const int YB = (N + 63) / 64;

    // ws (ints): flag[4] | boff[NB+1] | gcur[NB] | pairs[E] (head aliased as
    // ghist partials: GB*NB ints) | y[N*64 bf16]
    size_t ints = (size_t)4 + (NB + 1) + NB + E;
    size_t need1 = ints * sizeof(int) + (size_t)N * 64 * sizeof(unsigned short);
    bool alias_ok = (size_t)GB * NB <= (size_t)E;

    if (NB <= NBMAX && alias_ok && ws_size >= need1) {
        int* flag = (int*)d_ws;
        int* boff = flag + 4;
        int* gcur = boff + (NB + 1);
        int* pairs = gcur + NB;
        unsigned short* y = (unsigned short*)(pairs + E);

        k_ghist2<<<GB, 1024, 0, stream>>>(ei, pairs, flag, E, NB);
        k_mega<<<1 + PB + YB, 1024, 0, stream>>>(ei, x, W, flag, boff, gcur,
                                                 pairs, y, E, N, NB, PB);
        k_bgather16<<<NB, 1024, 0, stream>>>(y, (const unsigned*)pairs, boff, out, N);
    } else if (NB <= NBMAX && ws_size >= ((size_t)NB * 3 + 1 + E) * sizeof(int)
                                        + (size_t)N * 64 * sizeof(unsigned short)) {
        // tier-2: R8 path
        int* gcnt = (int*)d_ws;
        int* boff = gcnt + NB;
        int* gcur = boff + (NB + 1);
        unsigned* pairs = (unsigned*)(gcur + NB);
        unsigned short* y = (unsigned short*)(pairs + E);

        hipMemsetAsync(gcnt, 0, (size_t)NB * sizeof(int), stream);
        k_ghist<<<128, 1024, 0, stream>>>(ei, gcnt, E, NB);
        k_gscan<<<1, 1024, 0, stream>>>(gcnt, boff, gcur, NB, E);
        k_pairs<<<PB, 1024, 0, stream>>>(ei, gcur, pairs, E, NB);
        k_ytrans2<<<YB, 256, 0, stream>>>(x, W, y, N);
        k_bgather16<<<NB, 1024, 0, stream>>>(y, pairs, boff, out, N);
    } else {
        hipMemsetAsync(out, 0, (size_t)N * 64 * sizeof(float), stream);
        long sthreads = (long)E * 16;
        egat_scatter<<<(int)((sthreads + 255) / 256), 256, 0, stream>>>(x, ei, out, E);
        egat_transform<<<(N + 15) / 16, 256, 0, stream>>>(out, W, N);
    }
}